// Round 1
// baseline (1061.437 us; speedup 1.0000x reference)
//
#include <hip/hip_runtime.h>
#include <math.h>

#define SEQ 4096
#define DIM 1024

constexpr int BM = 64, BN = 64, BK = 16, TM = 4, TN = 4;
// block = dim3(16,16) = 256 threads, each thread computes a 4x4 micro-tile.

// ---------------------------------------------------------------------------
// NN SGEMM: C[M,N] = A[M,K] @ B[K,N], row-major. If causal_kbound, only
// accumulate k < row0+BM (valid because P's masked region is exactly zero).
// ---------------------------------------------------------------------------
__global__ __launch_bounds__(256) void gemm_nn(const float* __restrict__ A,
                                               const float* __restrict__ B,
                                               float* __restrict__ C,
                                               int M, int N, int K,
                                               int causal_kbound) {
    __shared__ float As[BK][BM];
    __shared__ float Bs[BK][BN];
    const int tid = threadIdx.y * 16 + threadIdx.x;
    const int row0 = blockIdx.y * BM;
    const int col0 = blockIdx.x * BN;
    const int kend = causal_kbound ? min(K, row0 + BM) : K;

    // A tile load map: 64 rows x 16 k, one float4 along k per thread
    const int am = tid >> 2;
    const int ak = (tid & 3) * 4;
    // B tile load map: 16 k x 64 n, one float4 along n per thread
    const int bk = tid >> 4;
    const int bn = (tid & 15) * 4;

    float acc[TM][TN] = {};

    for (int k0 = 0; k0 < kend; k0 += BK) {
        const float4 a4 = *(const float4*)(A + (size_t)(row0 + am) * K + k0 + ak);
        As[ak + 0][am] = a4.x;
        As[ak + 1][am] = a4.y;
        As[ak + 2][am] = a4.z;
        As[ak + 3][am] = a4.w;
        *(float4*)&Bs[bk][bn] = *(const float4*)(B + (size_t)(k0 + bk) * N + col0 + bn);
        __syncthreads();
#pragma unroll
        for (int kk = 0; kk < BK; ++kk) {
            float ra[TM], rb[TN];
#pragma unroll
            for (int i = 0; i < TM; ++i) ra[i] = As[kk][threadIdx.y * TM + i];
#pragma unroll
            for (int j = 0; j < TN; ++j) rb[j] = Bs[kk][threadIdx.x * TN + j];
#pragma unroll
            for (int i = 0; i < TM; ++i)
#pragma unroll
                for (int j = 0; j < TN; ++j)
                    acc[i][j] = fmaf(ra[i], rb[j], acc[i][j]);
        }
        __syncthreads();
    }

#pragma unroll
    for (int i = 0; i < TM; ++i) {
        const int r = row0 + threadIdx.y * TM + i;
        float4 v = make_float4(acc[i][0], acc[i][1], acc[i][2], acc[i][3]);
        *(float4*)(C + (size_t)r * N + col0 + threadIdx.x * TN) = v;
    }
}

// ---------------------------------------------------------------------------
// NT SGEMM for scores: P[i,j] = sum_k Q[i,k]*Km[j,k]. Blocks entirely above
// the causal diagonal are skipped (softmax kernel overwrites them with 0).
// ---------------------------------------------------------------------------
__global__ __launch_bounds__(256) void gemm_nt_scores(const float* __restrict__ Q,
                                                      const float* __restrict__ Km,
                                                      float* __restrict__ P) {
    const int row0 = blockIdx.y * BM;
    const int col0 = blockIdx.x * BN;
    if (col0 > row0) return;  // fully masked block (col0 >= row0+64 > row_max)

    __shared__ float As[BK][BM];
    __shared__ float Bs[BK][BN];
    const int tid = threadIdx.y * 16 + threadIdx.x;
    const int am = tid >> 2;
    const int ak = (tid & 3) * 4;

    float acc[TM][TN] = {};

    for (int k0 = 0; k0 < DIM; k0 += BK) {
        const float4 a4 = *(const float4*)(Q + (size_t)(row0 + am) * DIM + k0 + ak);
        As[ak + 0][am] = a4.x;
        As[ak + 1][am] = a4.y;
        As[ak + 2][am] = a4.z;
        As[ak + 3][am] = a4.w;
        const float4 b4 = *(const float4*)(Km + (size_t)(col0 + am) * DIM + k0 + ak);
        Bs[ak + 0][am] = b4.x;
        Bs[ak + 1][am] = b4.y;
        Bs[ak + 2][am] = b4.z;
        Bs[ak + 3][am] = b4.w;
        __syncthreads();
#pragma unroll
        for (int kk = 0; kk < BK; ++kk) {
            float ra[TM], rb[TN];
#pragma unroll
            for (int i = 0; i < TM; ++i) ra[i] = As[kk][threadIdx.y * TM + i];
#pragma unroll
            for (int j = 0; j < TN; ++j) rb[j] = Bs[kk][threadIdx.x * TN + j];
#pragma unroll
            for (int i = 0; i < TM; ++i)
#pragma unroll
                for (int j = 0; j < TN; ++j)
                    acc[i][j] = fmaf(ra[i], rb[j], acc[i][j]);
        }
        __syncthreads();
    }

#pragma unroll
    for (int i = 0; i < TM; ++i) {
        const int r = row0 + threadIdx.y * TM + i;
        float4 v = make_float4(acc[i][0], acc[i][1], acc[i][2], acc[i][3]);
        *(float4*)(P + (size_t)r * SEQ + col0 + threadIdx.x * TN) = v;
    }
}

// ---------------------------------------------------------------------------
// Causal row softmax in-place on P, one block per row. Scale = 1/sqrt(1024).
// Writes exact zeros into the masked (upper-triangle) region.
// ---------------------------------------------------------------------------
__global__ __launch_bounds__(256) void softmax_causal(float* __restrict__ P) {
    __shared__ float red[4];
    __shared__ float bcast;
    const int i = blockIdx.x;
    float* row = P + (size_t)i * SEQ;
    const int n = i + 1;
    const float scale = 0.03125f;  // 1/32
    const int tid = threadIdx.x;

    float m = -3.4e38f;
    for (int j = tid; j < n; j += 256) m = fmaxf(m, row[j]);
#pragma unroll
    for (int o = 32; o > 0; o >>= 1) m = fmaxf(m, __shfl_down(m, o));
    if ((tid & 63) == 0) red[tid >> 6] = m;
    __syncthreads();
    if (tid == 0) bcast = fmaxf(fmaxf(red[0], red[1]), fmaxf(red[2], red[3]));
    __syncthreads();
    m = bcast * scale;

    float s = 0.f;
    for (int j = tid; j < n; j += 256) s += __expf(row[j] * scale - m);
#pragma unroll
    for (int o = 32; o > 0; o >>= 1) s += __shfl_down(s, o);
    if ((tid & 63) == 0) red[tid >> 6] = s;
    __syncthreads();
    if (tid == 0) bcast = 1.0f / (red[0] + red[1] + red[2] + red[3]);
    __syncthreads();
    const float inv = bcast;

    for (int j = tid; j < n; j += 256) row[j] = __expf(row[j] * scale - m) * inv;
    for (int j = n + tid; j < SEQ; j += 256) row[j] = 0.f;
}

extern "C" void kernel_launch(void* const* d_in, const int* in_sizes, int n_in,
                              void* d_out, int out_size, void* d_ws, size_t ws_size,
                              hipStream_t stream) {
    const float* x  = (const float*)d_in[0];
    const float* Wq = (const float*)d_in[1];
    const float* Wk = (const float*)d_in[2];
    const float* Wv = (const float*)d_in[3];
    float* O = (float*)d_out;

    // Workspace layout (fp32): Q | K | V | P  = 16+16+16+64 = 112 MB
    float* Q = (float*)d_ws;
    float* K = Q + (size_t)SEQ * DIM;
    float* V = K + (size_t)SEQ * DIM;
    float* P = V + (size_t)SEQ * DIM;

    dim3 blk(16, 16);

    // QKV projections: [4096,1024] @ [1024,1024]
    dim3 gproj(DIM / BN, SEQ / BM);
    gemm_nn<<<gproj, blk, 0, stream>>>(x, Wq, Q, SEQ, DIM, DIM, 0);
    gemm_nn<<<gproj, blk, 0, stream>>>(x, Wk, K, SEQ, DIM, DIM, 0);
    gemm_nn<<<gproj, blk, 0, stream>>>(x, Wv, V, SEQ, DIM, DIM, 0);

    // Scores: P = Q @ K^T (lower-triangle blocks only)
    dim3 gsc(SEQ / BN, SEQ / BM);
    gemm_nt_scores<<<gsc, blk, 0, stream>>>(Q, K, P);

    // Causal softmax in-place (also zero-fills the masked region)
    softmax_causal<<<SEQ, 256, 0, stream>>>(P);

    // O = P @ V with causal k-bound
    dim3 gpv(DIM / BN, SEQ / BM);
    gemm_nn<<<gpv, blk, 0, stream>>>(P, V, O, SEQ, DIM, SEQ, 1);
}

// Round 2
// 318.369 us; speedup vs baseline: 3.3340x; 3.3340x over previous
//
#include <hip/hip_runtime.h>
#include <math.h>

#define SEQ 4096
#define DIM 1024

typedef unsigned short u16;
typedef __attribute__((ext_vector_type(8))) short short8;     // 8 x bf16 (4 VGPRs)
typedef __attribute__((ext_vector_type(4))) float floatx4;    // MFMA accumulator
typedef __attribute__((ext_vector_type(4))) unsigned short us4;

__device__ __forceinline__ float bf2f(u16 u) {
    union { unsigned int i; float f; } c; c.i = ((unsigned int)u) << 16; return c.f;
}
__device__ __forceinline__ u16 f2bf(float f) {
    union { float f; unsigned int i; } c; c.f = f;
    return (u16)((c.i + 0x7fffu + ((c.i >> 16) & 1u)) >> 16);  // RNE
}

__device__ __forceinline__ void gload_lds16(const u16* g, u16* l) {
    __builtin_amdgcn_global_load_lds((const __attribute__((address_space(1))) void*)g,
                                     (__attribute__((address_space(3))) void*)l, 16, 0, 0);
}

// ---------------------------------------------------------------------------
// NT MFMA GEMM: C[m][n] = out_scale * sum_k A[m][k] * B[n][k]   (bf16 in)
// 128x128 tile, BK=32, 256 threads = 4 waves in 2x2, each wave 64x64 via
// 4x4 of mfma_f32_16x16x32_bf16. A,B staged to LDS with global_load_lds x16.
// SKIP_UPPER: skip blocks with col0 > row0 (causal scores).
// KBOUND:     kend = row0+128 (PV with zeroed masked P region).
// ---------------------------------------------------------------------------
template <int OUT_BF16, int SKIP_UPPER, int KBOUND>
__global__ __launch_bounds__(256) void gemm_nt_mfma(const u16* __restrict__ A,
                                                    const u16* __restrict__ B,
                                                    void* __restrict__ Cv,
                                                    int M, int N, int K,
                                                    float out_scale) {
    const int row0 = blockIdx.y * 128;
    const int col0 = blockIdx.x * 128;
    if (SKIP_UPPER && col0 > row0) return;

    __shared__ u16 As[128 * 32];
    __shared__ u16 Bs[128 * 32];

    const int tid  = threadIdx.x;
    const int wave = tid >> 6;
    const int lane = tid & 63;
    const int wm = wave & 1;   // wave row within 2x2
    const int wn = wave >> 1;  // wave col

    // staging: 512 16B-chunks per tile; wave w covers chunks [w*128, w*128+128)
    const int ch0 = wave * 128 + lane;
    const int ch1 = ch0 + 64;
    const u16* aP0 = A + (size_t)(row0 + (ch0 >> 2)) * K + (ch0 & 3) * 8;
    const u16* aP1 = A + (size_t)(row0 + (ch1 >> 2)) * K + (ch1 & 3) * 8;
    const u16* bP0 = B + (size_t)(col0 + (ch0 >> 2)) * K + (ch0 & 3) * 8;
    const u16* bP1 = B + (size_t)(col0 + (ch1 >> 2)) * K + (ch1 & 3) * 8;
    u16* lA0 = &As[wave * 1024];
    u16* lA1 = &As[wave * 1024 + 512];
    u16* lB0 = &Bs[wave * 1024];
    u16* lB1 = &Bs[wave * 1024 + 512];

    floatx4 acc[4][4] = {};

    const int kend = KBOUND ? min(K, row0 + 128) : K;
    const int frow = lane & 15;         // A: m / B: n index within 16
    const int fk   = (lane >> 4) * 8;   // k offset within 32

    for (int k0 = 0; k0 < kend; k0 += 32) {
        __syncthreads();
        gload_lds16(aP0, lA0);
        gload_lds16(aP1, lA1);
        gload_lds16(bP0, lB0);
        gload_lds16(bP1, lB1);
        aP0 += 32; aP1 += 32; bP0 += 32; bP1 += 32;
        asm volatile("s_waitcnt vmcnt(0)" ::: "memory");
        __syncthreads();

        short8 af[4], bfr[4];
#pragma unroll
        for (int t = 0; t < 4; ++t) {
            af[t]  = *(const short8*)&As[(wm * 64 + t * 16 + frow) * 32 + fk];
            bfr[t] = *(const short8*)&Bs[(wn * 64 + t * 16 + frow) * 32 + fk];
        }
#pragma unroll
        for (int mt = 0; mt < 4; ++mt)
#pragma unroll
            for (int nt = 0; nt < 4; ++nt)
                acc[mt][nt] = __builtin_amdgcn_mfma_f32_16x16x32_bf16(
                    af[mt], bfr[nt], acc[mt][nt], 0, 0, 0);
    }

    // epilogue: C/D layout col=lane&15, row=(lane>>4)*4+reg
    const int cr = (lane >> 4) * 4;
    const int cc = lane & 15;
#pragma unroll
    for (int mt = 0; mt < 4; ++mt) {
#pragma unroll
        for (int nt = 0; nt < 4; ++nt) {
#pragma unroll
            for (int r = 0; r < 4; ++r) {
                const int row = row0 + wm * 64 + mt * 16 + cr + r;
                const int col = col0 + wn * 64 + nt * 16 + cc;
                const float v = acc[mt][nt][r] * out_scale;
                if (OUT_BF16)
                    ((u16*)Cv)[(size_t)row * N + col] = f2bf(v);
                else
                    ((float*)Cv)[(size_t)row * N + col] = v;
            }
        }
    }
}

// fp32 [k][n] -> bf16 [n][k] (weights, 1024x1024)
__global__ __launch_bounds__(256) void transpose_cast(const float* __restrict__ W,
                                                      u16* __restrict__ Wt) {
    __shared__ float tile[32][33];
    const int bx = blockIdx.x * 32;  // n block
    const int by = blockIdx.y * 32;  // k block
    const int tx = threadIdx.x & 31;
    const int ty = (threadIdx.x >> 5) * 4;
#pragma unroll
    for (int r = 0; r < 4; ++r)
        tile[ty + r][tx] = W[(size_t)(by + ty + r) * DIM + bx + tx];
    __syncthreads();
#pragma unroll
    for (int r = 0; r < 4; ++r)
        Wt[(size_t)(bx + ty + r) * DIM + by + tx] = f2bf(tile[tx][ty + r]);
}

// fp32 -> bf16 flat cast (x)
__global__ __launch_bounds__(256) void cast_bf16(const float* __restrict__ X,
                                                 u16* __restrict__ Xb) {
    const size_t i = ((size_t)blockIdx.x * 256 + threadIdx.x) * 4;
    const float4 v = *(const float4*)(X + i);
    us4 o = { f2bf(v.x), f2bf(v.y), f2bf(v.z), f2bf(v.w) };
    *(us4*)(Xb + i) = o;
}

// causal softmax, in-place on bf16 scores (scale already folded into Q).
// one block per row; zeros the masked tail so PV can use a k-bound.
__global__ __launch_bounds__(256) void softmax_causal_bf16(u16* __restrict__ S) {
    __shared__ float red[4];
    __shared__ float bc;
    const int i = blockIdx.x;
    u16* row = S + (size_t)i * SEQ;
    const int n = i + 1;
    const int tid = threadIdx.x;

    float m = -3.4e38f;
    for (int j = tid; j < n; j += 256) m = fmaxf(m, bf2f(row[j]));
#pragma unroll
    for (int o = 32; o > 0; o >>= 1) m = fmaxf(m, __shfl_down(m, o));
    if ((tid & 63) == 0) red[tid >> 6] = m;
    __syncthreads();
    if (tid == 0) bc = fmaxf(fmaxf(red[0], red[1]), fmaxf(red[2], red[3]));
    __syncthreads();
    m = bc;

    float s = 0.f;
    for (int j = tid; j < n; j += 256) s += __expf(bf2f(row[j]) - m);
#pragma unroll
    for (int o = 32; o > 0; o >>= 1) s += __shfl_down(s, o);
    if ((tid & 63) == 0) red[tid >> 6] = s;
    __syncthreads();
    if (tid == 0) bc = 1.0f / (red[0] + red[1] + red[2] + red[3]);
    __syncthreads();
    const float inv = bc;

    for (int j = tid; j < n; j += 256) row[j] = f2bf(__expf(bf2f(row[j]) - m) * inv);
    for (int j = n + tid; j < SEQ; j += 256) row[j] = 0;
}

extern "C" void kernel_launch(void* const* d_in, const int* in_sizes, int n_in,
                              void* d_out, int out_size, void* d_ws, size_t ws_size,
                              hipStream_t stream) {
    const float* x  = (const float*)d_in[0];
    const float* Wq = (const float*)d_in[1];
    const float* Wk = (const float*)d_in[2];
    const float* Wv = (const float*)d_in[3];

    // ws layout (bf16 elements): xb 8MB | Wqt/Wkt/Wvt 2MB ea | Qb 8 | Kb 8 | Vt 8 | S 32  = 70 MB
    u16* xb  = (u16*)d_ws;
    u16* Wqt = xb  + (size_t)SEQ * DIM;
    u16* Wkt = Wqt + (size_t)DIM * DIM;
    u16* Wvt = Wkt + (size_t)DIM * DIM;
    u16* Qb  = Wvt + (size_t)DIM * DIM;
    u16* Kb  = Qb  + (size_t)SEQ * DIM;
    u16* Vt  = Kb  + (size_t)SEQ * DIM;
    u16* S   = Vt  + (size_t)DIM * SEQ;

    cast_bf16<<<SEQ * DIM / 1024, 256, 0, stream>>>(x, xb);
    dim3 tgrid(32, 32);
    transpose_cast<<<tgrid, 256, 0, stream>>>(Wq, Wqt);
    transpose_cast<<<tgrid, 256, 0, stream>>>(Wk, Wkt);
    transpose_cast<<<tgrid, 256, 0, stream>>>(Wv, Wvt);

    // Q = (x @ Wq) / 32  (scale folded, exact in bf16);  K likewise unscaled
    gemm_nt_mfma<1, 0, 0><<<dim3(DIM / 128, SEQ / 128), 256, 0, stream>>>(
        xb, Wqt, Qb, SEQ, DIM, DIM, 0.03125f);
    gemm_nt_mfma<1, 0, 0><<<dim3(DIM / 128, SEQ / 128), 256, 0, stream>>>(
        xb, Wkt, Kb, SEQ, DIM, DIM, 1.0f);
    // Vt[n][j] = V[j][n]: A=Wvt (M=DIM), B=xb (N=SEQ)
    gemm_nt_mfma<1, 0, 0><<<dim3(SEQ / 128, DIM / 128), 256, 0, stream>>>(
        Wvt, xb, Vt, DIM, SEQ, DIM, 1.0f);
    // S = Qb @ Kb^T (bf16, lower-triangle blocks only)
    gemm_nt_mfma<1, 1, 0><<<dim3(SEQ / 128, SEQ / 128), 256, 0, stream>>>(
        Qb, Kb, S, SEQ, SEQ, DIM, 1.0f);
    softmax_causal_bf16<<<SEQ, 256, 0, stream>>>(S);
    // O = P @ V = S @ Vt^T with causal k-bound, fp32 out
    gemm_nt_mfma<0, 0, 1><<<dim3(DIM / 128, SEQ / 128), 256, 0, stream>>>(
        S, Vt, d_out, SEQ, DIM, SEQ, 1.0f);
}

// Round 3
// 232.791 us; speedup vs baseline: 4.5596x; 1.3676x over previous
//
#include <hip/hip_runtime.h>
#include <math.h>

#define SEQ 4096
#define DIM 1024

typedef unsigned short u16;
typedef __attribute__((ext_vector_type(8))) short short8;     // 8 x bf16 (4 VGPRs)
typedef __attribute__((ext_vector_type(4))) float floatx4;    // MFMA accumulator
typedef __attribute__((ext_vector_type(4))) unsigned short us4;

__device__ __forceinline__ float bf2f(u16 u) {
    union { unsigned int i; float f; } c; c.i = ((unsigned int)u) << 16; return c.f;
}
__device__ __forceinline__ u16 f2bf(float f) {
    union { float f; unsigned int i; } c; c.f = f;
    return (u16)((c.i + 0x7fffu + ((c.i >> 16) & 1u)) >> 16);  // RNE
}
__device__ __forceinline__ void gload_lds16(const u16* g, u16* l) {
    __builtin_amdgcn_global_load_lds((const __attribute__((address_space(1))) void*)g,
                                     (__attribute__((address_space(3))) void*)l, 16, 0, 0);
}

// ---------------------------------------------------------------------------
// NT MFMA GEMM, 128x128 tile, BK=32, 4 waves (2x2), 4x4 mfma_16x16x32_bf16
// per wave. Single-barrier pipelined K-loop: LDS double-buffered; the
// prefetch for tile k+1 is issued right AFTER the barrier so the compiler's
// vmcnt(0)-before-s_barrier drains loads that had a full iteration in flight.
// MODE 0: bf16 out, per-col-block scale (scale0 if col0<1024 else scale1)
// MODE 1: bf16 out, skip blocks above causal diagonal
// MODE 2: fp32 out, split-K over blockIdx.z (chunks of 1024, causal k-bound);
//         chunk 0 -> Cv direct, chunks 1..3 -> compact partial buffers.
// ---------------------------------------------------------------------------
template <int MODE>
__global__ __launch_bounds__(256) void gemm_nt(const u16* __restrict__ A,
                                               const u16* __restrict__ B,
                                               void* __restrict__ Cv,
                                               float* __restrict__ Ppart,
                                               int lda, int ldb, int ldc, int Kdim,
                                               float scale0, float scale1) {
    const int row0 = blockIdx.y * 128;
    const int col0 = blockIdx.x * 128;
    if (MODE == 1 && col0 > row0) return;
    int kbeg = 0, kend = Kdim, chunk = 0;
    if (MODE == 2) {
        chunk = blockIdx.z;
        kbeg = chunk << 10;
        const int klim = row0 + 128;
        if (kbeg >= klim) return;
        kend = min(kbeg + 1024, klim);
    }

    __shared__ u16 As[2][4096];  // 2 x 8KB
    __shared__ u16 Bs[2][4096];

    const int tid  = threadIdx.x;
    const int wave = tid >> 6;
    const int lane = tid & 63;
    const int wm = wave & 1;
    const int wn = wave >> 1;

    // staging map: 512 16B-chunks per tile; wave w covers chunks [w*128, w*128+128)
    const int ch0 = wave * 128 + lane;
    const int ch1 = ch0 + 64;
    const u16* aP0 = A + (size_t)(row0 + (ch0 >> 2)) * lda + kbeg + (ch0 & 3) * 8;
    const u16* aP1 = A + (size_t)(row0 + (ch1 >> 2)) * lda + kbeg + (ch1 & 3) * 8;
    const u16* bP0 = B + (size_t)(col0 + (ch0 >> 2)) * ldb + kbeg + (ch0 & 3) * 8;
    const u16* bP1 = B + (size_t)(col0 + (ch1 >> 2)) * ldb + kbeg + (ch1 & 3) * 8;
    const int l0 = wave * 1024;

    floatx4 acc[4][4] = {};
    const int niter = (kend - kbeg) >> 5;
    const int frow = lane & 15;
    const int fk   = (lane >> 4) * 8;

    // prologue: stage tile 0 into buffer 0
    gload_lds16(aP0, &As[0][l0]);
    gload_lds16(aP1, &As[0][l0 + 512]);
    gload_lds16(bP0, &Bs[0][l0]);
    gload_lds16(bP1, &Bs[0][l0 + 512]);
    aP0 += 32; aP1 += 32; bP0 += 32; bP1 += 32;

    for (int it = 0; it < niter; ++it) {
        const int cur = it & 1;
        __syncthreads();  // drains tile-it loads (in flight one full iteration)
        if (it + 1 < niter) {
            const int nxt = cur ^ 1;
            gload_lds16(aP0, &As[nxt][l0]);
            gload_lds16(aP1, &As[nxt][l0 + 512]);
            gload_lds16(bP0, &Bs[nxt][l0]);
            gload_lds16(bP1, &Bs[nxt][l0 + 512]);
            aP0 += 32; aP1 += 32; bP0 += 32; bP1 += 32;
        }
        __builtin_amdgcn_sched_barrier(0);  // keep prefetch issue ahead of compute
        short8 af[4], bfr[4];
#pragma unroll
        for (int t = 0; t < 4; ++t) {
            af[t]  = *(const short8*)&As[cur][(wm * 64 + t * 16 + frow) * 32 + fk];
            bfr[t] = *(const short8*)&Bs[cur][(wn * 64 + t * 16 + frow) * 32 + fk];
        }
#pragma unroll
        for (int mt = 0; mt < 4; ++mt)
#pragma unroll
            for (int nt = 0; nt < 4; ++nt)
                acc[mt][nt] = __builtin_amdgcn_mfma_f32_16x16x32_bf16(
                    af[mt], bfr[nt], acc[mt][nt], 0, 0, 0);
    }

    // epilogue: C/D layout col=lane&15, row=(lane>>4)*4+reg
    const int cr = (lane >> 4) * 4;
    const int cc = lane & 15;
    if (MODE == 2) {
        float* dst;
        if (chunk == 0) {
            dst = (float*)Cv;
        } else {
            const ptrdiff_t poff[3] = {0, (ptrdiff_t)3072 * 1024, (ptrdiff_t)5120 * 1024};
            dst = Ppart + poff[chunk - 1] - (ptrdiff_t)(chunk << 10) * 1024;
        }
#pragma unroll
        for (int mt = 0; mt < 4; ++mt)
#pragma unroll
            for (int nt = 0; nt < 4; ++nt)
#pragma unroll
                for (int r = 0; r < 4; ++r) {
                    const int row = row0 + wm * 64 + mt * 16 + cr + r;
                    const int col = col0 + wn * 64 + nt * 16 + cc;
                    dst[(size_t)row * ldc + col] = acc[mt][nt][r];
                }
    } else {
        u16* dst = (u16*)Cv;
        const float sc = (col0 < 1024) ? scale0 : scale1;
#pragma unroll
        for (int mt = 0; mt < 4; ++mt)
#pragma unroll
            for (int nt = 0; nt < 4; ++nt)
#pragma unroll
                for (int r = 0; r < 4; ++r) {
                    const int row = row0 + wm * 64 + mt * 16 + cr + r;
                    const int col = col0 + wn * 64 + nt * 16 + cc;
                    dst[(size_t)row * ldc + col] = f2bf(acc[mt][nt][r] * sc);
                }
    }
}

// fp32 [k][n] -> bf16 [n][k]; blockIdx.z selects Wq/Wk/Wv, stacked [3072][1024]
__global__ __launch_bounds__(256) void transpose_cast(const float* __restrict__ W0,
                                                      const float* __restrict__ W1,
                                                      const float* __restrict__ W2,
                                                      u16* __restrict__ Wt) {
    __shared__ float tile[32][33];
    const float* W = (blockIdx.z == 0) ? W0 : (blockIdx.z == 1) ? W1 : W2;
    u16* out = Wt + (size_t)blockIdx.z * DIM * DIM;
    const int bx = blockIdx.x * 32;  // n block
    const int by = blockIdx.y * 32;  // k block
    const int tx = threadIdx.x & 31;
    const int ty = (threadIdx.x >> 5) * 4;
#pragma unroll
    for (int r = 0; r < 4; ++r)
        tile[ty + r][tx] = W[(size_t)(by + ty + r) * DIM + bx + tx];
    __syncthreads();
#pragma unroll
    for (int r = 0; r < 4; ++r)
        out[(size_t)(bx + ty + r) * DIM + by + tx] = f2bf(tile[tx][ty + r]);
}

// fp32 -> bf16 flat cast (x)
__global__ __launch_bounds__(256) void cast_bf16(const float* __restrict__ X,
                                                 u16* __restrict__ Xb) {
    const size_t i = ((size_t)blockIdx.x * 256 + threadIdx.x) * 4;
    const float4 v = *(const float4*)(X + i);
    us4 o = { f2bf(v.x), f2bf(v.y), f2bf(v.z), f2bf(v.w) };
    *(us4*)(Xb + i) = o;
}

// bf16 transpose of V (QKV cols 2048..3071) -> Vt[1024][4096]
__global__ __launch_bounds__(256) void transpose_v(const u16* __restrict__ QKV,
                                                   u16* __restrict__ Vt) {
    __shared__ u16 t[64][68];  // stride 136B: 8B-aligned rows
    const int vc0 = blockIdx.x * 64;  // V col block
    const int vr0 = blockIdx.y * 64;  // V row block
    const int tid = threadIdx.x;
    const int tx4 = (tid & 15) * 4;
    const int r0 = tid >> 4;  // 0..15
#pragma unroll
    for (int p = 0; p < 4; ++p) {
        const int r = r0 + p * 16;
        *(us4*)&t[r][tx4] = *(const us4*)&QKV[(size_t)(vr0 + r) * 3072 + 2048 + vc0 + tx4];
    }
    __syncthreads();
#pragma unroll
    for (int p = 0; p < 4; ++p) {
        const int c = r0 + p * 16;
        us4 o = { t[tx4 + 0][c], t[tx4 + 1][c], t[tx4 + 2][c], t[tx4 + 3][c] };
        *(us4*)&Vt[(size_t)(vc0 + c) * SEQ + vr0 + tx4] = o;
    }
}

// causal softmax, single-pass (register-cached), in-place bf16.
// Zeroes only cols [n, diag-block edge) — all PV ever reads.
__global__ __launch_bounds__(256) void softmax_causal_bf16(u16* __restrict__ S) {
    __shared__ float red[4];
    __shared__ float bc;
    const int i = blockIdx.x;
    u16* row = S + (size_t)i * SEQ;
    const int n = i + 1;
    const int tid = threadIdx.x;
    const int zend = (i & ~127) + 128;

    float v[16];
    float m = -3.4e38f;
#pragma unroll
    for (int t = 0; t < 16; ++t) {
        const int j = tid + (t << 8);
        if (j < n) { v[t] = bf2f(row[j]); m = fmaxf(m, v[t]); }
    }
#pragma unroll
    for (int o = 32; o > 0; o >>= 1) m = fmaxf(m, __shfl_down(m, o));
    if ((tid & 63) == 0) red[tid >> 6] = m;
    __syncthreads();
    if (tid == 0) bc = fmaxf(fmaxf(red[0], red[1]), fmaxf(red[2], red[3]));
    __syncthreads();
    m = bc;

    float s = 0.f;
#pragma unroll
    for (int t = 0; t < 16; ++t) {
        const int j = tid + (t << 8);
        if (j < n) { v[t] = __expf(v[t] - m); s += v[t]; }
    }
#pragma unroll
    for (int o = 32; o > 0; o >>= 1) s += __shfl_down(s, o);
    if ((tid & 63) == 0) red[tid >> 6] = s;
    __syncthreads();
    if (tid == 0) bc = 1.0f / (red[0] + red[1] + red[2] + red[3]);
    __syncthreads();
    const float inv = bc;

#pragma unroll
    for (int t = 0; t < 16; ++t) {
        const int j = tid + (t << 8);
        if (j < n) row[j] = f2bf(v[t] * inv);
        else if (j < zend) row[j] = 0;
    }
}

// O[row] += partials, rows 1024..4095; one block per row, float4 lanes
__global__ __launch_bounds__(256) void reduce_pv(float* __restrict__ O,
                                                 const float* __restrict__ P) {
    const int r = blockIdx.x;  // 0..3071
    const int row = 1024 + r;
    const int col = threadIdx.x * 4;
    float4 a = *(const float4*)(O + (size_t)row * 1024 + col);
    const float4 b1 = *(const float4*)(P + (size_t)r * 1024 + col);
    a.x += b1.x; a.y += b1.y; a.z += b1.z; a.w += b1.w;
    if (row >= 2048) {
        const float4 b2 = *(const float4*)(P + (size_t)3072 * 1024 +
                                           (size_t)(row - 2048) * 1024 + col);
        a.x += b2.x; a.y += b2.y; a.z += b2.z; a.w += b2.w;
    }
    if (row >= 3072) {
        const float4 b3 = *(const float4*)(P + (size_t)5120 * 1024 +
                                           (size_t)(row - 3072) * 1024 + col);
        a.x += b3.x; a.y += b3.y; a.z += b3.z; a.w += b3.w;
    }
    *(float4*)(O + (size_t)row * 1024 + col) = a;
}

extern "C" void kernel_launch(void* const* d_in, const int* in_sizes, int n_in,
                              void* d_out, int out_size, void* d_ws, size_t ws_size,
                              hipStream_t stream) {
    const float* x  = (const float*)d_in[0];
    const float* Wq = (const float*)d_in[1];
    const float* Wk = (const float*)d_in[2];
    const float* Wv = (const float*)d_in[3];

    // ws: xb 8MB | Wt 6MB | QKV 24MB | Vt 8MB | S 32MB | Ppart 24MB = 102 MB
    u16* xb    = (u16*)d_ws;
    u16* Wt    = xb  + (size_t)SEQ * DIM;
    u16* QKV   = Wt  + (size_t)3072 * DIM;
    u16* Vt    = QKV + (size_t)SEQ * 3072;
    u16* S     = Vt  + (size_t)DIM * SEQ;
    float* Ppart = (float*)(S + (size_t)SEQ * SEQ);

    cast_bf16<<<SEQ * DIM / 1024, 256, 0, stream>>>(x, xb);
    transpose_cast<<<dim3(32, 32, 3), 256, 0, stream>>>(Wq, Wk, Wv, Wt);

    // QKV = x @ [Wq|Wk|Wv], Q scaled by 1/32 (exact in bf16). 768 blocks.
    gemm_nt<0><<<dim3(24, 32), 256, 0, stream>>>(
        xb, Wt, QKV, nullptr, DIM, DIM, 3072, DIM, 0.03125f, 1.0f);

    // Vt[1024][4096] from QKV's V columns. 1024 blocks.
    transpose_v<<<dim3(16, 64), 256, 0, stream>>>(QKV, Vt);

    // S = Q @ K^T, lower-triangle blocks. 528 active blocks.
    gemm_nt<1><<<dim3(32, 32), 256, 0, stream>>>(
        QKV, QKV + 1024, S, nullptr, 3072, 3072, SEQ, DIM, 1.0f, 1.0f);

    softmax_causal_bf16<<<SEQ, 256, 0, stream>>>(S);

    // O = P @ Vt^T, split-K (chunks of 1024, causal-bounded). 640 active blocks.
    gemm_nt<2><<<dim3(8, 32, 4), 256, 0, stream>>>(
        S, Vt, d_out, Ppart, SEQ, SEQ, DIM, SEQ, 1.0f, 1.0f);

    reduce_pv<<<3072, 256, 0, stream>>>((float*)d_out, Ppart);
}

// Round 4
// 224.595 us; speedup vs baseline: 4.7260x; 1.0365x over previous
//
#include <hip/hip_runtime.h>
#include <math.h>

#define SEQ 4096
#define DIM 1024

typedef unsigned short u16;
typedef __attribute__((ext_vector_type(8))) short short8;     // 8 x bf16 (4 VGPRs)
typedef __attribute__((ext_vector_type(4))) float floatx4;    // MFMA accumulator
typedef __attribute__((ext_vector_type(4))) unsigned short us4;

__device__ __forceinline__ float bf2f(u16 u) {
    union { unsigned int i; float f; } c; c.i = ((unsigned int)u) << 16; return c.f;
}
__device__ __forceinline__ u16 f2bf(float f) {
    union { float f; unsigned int i; } c; c.f = f;
    return (u16)((c.i + 0x7fffu + ((c.i >> 16) & 1u)) >> 16);  // RNE
}
__device__ __forceinline__ void gload_lds16(const u16* g, u16* l) {
    __builtin_amdgcn_global_load_lds((const __attribute__((address_space(1))) void*)g,
                                     (__attribute__((address_space(3))) void*)l, 16, 0, 0);
}

// ---------------------------------------------------------------------------
// NT MFMA GEMM, 128x128 tile, BK=32, 4 waves (2x2), 4x4 mfma_16x16x32_bf16.
// LDS double-buffered single-barrier pipeline; prefetch issued right after
// the barrier so the mandatory vmcnt(0)-before-s_barrier drains loads that
// had a full iteration in flight.
// XOR-swizzled LDS chunk layout: global 16B-chunk (r,q) lives at LDS slot
// r*4 + (q ^ ((r>>1)&3)). Staging keeps the lane-contiguous dest required by
// global_load_lds (we swizzle the SOURCE pointer); fragment reads land 2
// lanes per bank-group per phase (conflict-free) instead of 8-way.
// MODE 0: bf16 out; col0<2048 -> C (scale0 if col0<1024 else 1.0);
//         col0>=2048 -> transposed write into VtOut (V^T, us4-packed).
// MODE 1: bf16 out, skip blocks above causal diagonal (scores).
// MODE 2: fp32 out, split-K over blockIdx.z (1024-chunks, causal k-bound);
//         chunk 0 -> Cv direct, chunks 1..3 -> compact partial buffers.
// ---------------------------------------------------------------------------
template <int MODE>
__global__ __launch_bounds__(256) void gemm_nt(const u16* __restrict__ A,
                                               const u16* __restrict__ B,
                                               void* __restrict__ Cv,
                                               float* __restrict__ Ppart,
                                               u16* __restrict__ VtOut,
                                               int lda, int ldb, int ldc, int Kdim,
                                               float scale0) {
    const int row0 = blockIdx.y * 128;
    const int col0 = blockIdx.x * 128;
    if (MODE == 1 && col0 > row0) return;
    int kbeg = 0, kend = Kdim, chunk = 0;
    if (MODE == 2) {
        chunk = blockIdx.z;
        kbeg = chunk << 10;
        const int klim = row0 + 128;
        if (kbeg >= klim) return;
        kend = min(kbeg + 1024, klim);
    }

    __shared__ u16 As[2][4096];  // 2 x 8KB
    __shared__ u16 Bs[2][4096];

    const int tid  = threadIdx.x;
    const int wave = tid >> 6;
    const int lane = tid & 63;
    const int wm = wave & 1;
    const int wn = wave >> 1;

    // staging: 512 16B-slots per tile; wave w fills slots [w*128, w*128+128).
    // slot s <- global chunk (r = s>>2, q = (s&3) ^ ((s>>3)&3))
    const int s0 = wave * 128 + lane;
    const int s1 = s0 + 64;
    const int r0s = s0 >> 2, q0s = ((s0 & 3) ^ ((s0 >> 3) & 3)) * 8;
    const int r1s = s1 >> 2, q1s = ((s1 & 3) ^ ((s1 >> 3) & 3)) * 8;
    const u16* aP0 = A + (size_t)(row0 + r0s) * lda + kbeg + q0s;
    const u16* aP1 = A + (size_t)(row0 + r1s) * lda + kbeg + q1s;
    const u16* bP0 = B + (size_t)(col0 + r0s) * ldb + kbeg + q0s;
    const u16* bP1 = B + (size_t)(col0 + r1s) * ldb + kbeg + q1s;
    const int l0 = wave * 1024;

    floatx4 acc[4][4] = {};
    const int niter = (kend - kbeg) >> 5;
    const int frow = lane & 15;
    // swizzled k-chunk offset for fragment reads (elements)
    const int xq = (((lane >> 4) ^ ((frow >> 1) & 3))) * 8;

    gload_lds16(aP0, &As[0][l0]);
    gload_lds16(aP1, &As[0][l0 + 512]);
    gload_lds16(bP0, &Bs[0][l0]);
    gload_lds16(bP1, &Bs[0][l0 + 512]);
    aP0 += 32; aP1 += 32; bP0 += 32; bP1 += 32;

    for (int it = 0; it < niter; ++it) {
        const int cur = it & 1;
        __syncthreads();  // drains tile-it loads (in flight a full iteration)
        if (it + 1 < niter) {
            const int nxt = cur ^ 1;
            gload_lds16(aP0, &As[nxt][l0]);
            gload_lds16(aP1, &As[nxt][l0 + 512]);
            gload_lds16(bP0, &Bs[nxt][l0]);
            gload_lds16(bP1, &Bs[nxt][l0 + 512]);
            aP0 += 32; aP1 += 32; bP0 += 32; bP1 += 32;
        }
        __builtin_amdgcn_sched_barrier(0);  // keep prefetch issue ahead of compute
        short8 af[4], bfr[4];
#pragma unroll
        for (int t = 0; t < 4; ++t) {
            af[t]  = *(const short8*)&As[cur][(wm * 64 + t * 16 + frow) * 32 + xq];
            bfr[t] = *(const short8*)&Bs[cur][(wn * 64 + t * 16 + frow) * 32 + xq];
        }
#pragma unroll
        for (int mt = 0; mt < 4; ++mt)
#pragma unroll
            for (int nt = 0; nt < 4; ++nt)
                acc[mt][nt] = __builtin_amdgcn_mfma_f32_16x16x32_bf16(
                    af[mt], bfr[nt], acc[mt][nt], 0, 0, 0);
    }

    // epilogue: C/D layout col=lane&15, row=(lane>>4)*4+reg
    const int cr = (lane >> 4) * 4;
    const int cc = lane & 15;
    if (MODE == 2) {
        float* dst;
        if (chunk == 0) {
            dst = (float*)Cv;
        } else {
            const ptrdiff_t poff[3] = {0, (ptrdiff_t)3072 * 1024, (ptrdiff_t)5120 * 1024};
            dst = Ppart + poff[chunk - 1] - (ptrdiff_t)(chunk << 10) * 1024;
        }
#pragma unroll
        for (int mt = 0; mt < 4; ++mt)
#pragma unroll
            for (int nt = 0; nt < 4; ++nt)
#pragma unroll
                for (int r = 0; r < 4; ++r) {
                    const int row = row0 + wm * 64 + mt * 16 + cr + r;
                    const int col = col0 + wn * 64 + nt * 16 + cc;
                    dst[(size_t)row * ldc + col] = acc[mt][nt][r];
                }
    } else if (MODE == 0 && col0 >= 2048) {
        // V columns: write V^T directly. 4 consecutive regs = 4 consecutive
        // rows -> contiguous in Vt[col][row], pack as us4 (8B).
#pragma unroll
        for (int mt = 0; mt < 4; ++mt)
#pragma unroll
            for (int nt = 0; nt < 4; ++nt) {
                const int row = row0 + wm * 64 + mt * 16 + cr;
                const int col = (col0 - 2048) + wn * 64 + nt * 16 + cc;
                us4 o = { f2bf(acc[mt][nt][0]), f2bf(acc[mt][nt][1]),
                          f2bf(acc[mt][nt][2]), f2bf(acc[mt][nt][3]) };
                *(us4*)&VtOut[(size_t)col * SEQ + row] = o;
            }
    } else {
        u16* dst = (u16*)Cv;
        const float sc = (MODE == 0 && col0 < 1024) ? scale0 : 1.0f;
#pragma unroll
        for (int mt = 0; mt < 4; ++mt)
#pragma unroll
            for (int nt = 0; nt < 4; ++nt)
#pragma unroll
                for (int r = 0; r < 4; ++r) {
                    const int row = row0 + wm * 64 + mt * 16 + cr + r;
                    const int col = col0 + wn * 64 + nt * 16 + cc;
                    dst[(size_t)row * ldc + col] = f2bf(acc[mt][nt][r] * sc);
                }
    }
}

// fp32 [k][n] -> bf16 [n][k]; blockIdx.z selects Wq/Wk/Wv, stacked [3072][1024]
__global__ __launch_bounds__(256) void transpose_cast(const float* __restrict__ W0,
                                                      const float* __restrict__ W1,
                                                      const float* __restrict__ W2,
                                                      u16* __restrict__ Wt) {
    __shared__ float tile[32][33];
    const float* W = (blockIdx.z == 0) ? W0 : (blockIdx.z == 1) ? W1 : W2;
    u16* out = Wt + (size_t)blockIdx.z * DIM * DIM;
    const int bx = blockIdx.x * 32;  // n block
    const int by = blockIdx.y * 32;  // k block
    const int tx = threadIdx.x & 31;
    const int ty = (threadIdx.x >> 5) * 4;
#pragma unroll
    for (int r = 0; r < 4; ++r)
        tile[ty + r][tx] = W[(size_t)(by + ty + r) * DIM + bx + tx];
    __syncthreads();
#pragma unroll
    for (int r = 0; r < 4; ++r)
        out[(size_t)(bx + ty + r) * DIM + by + tx] = f2bf(tile[tx][ty + r]);
}

// fp32 -> bf16 flat cast (x)
__global__ __launch_bounds__(256) void cast_bf16(const float* __restrict__ X,
                                                 u16* __restrict__ Xb) {
    const size_t i = ((size_t)blockIdx.x * 256 + threadIdx.x) * 4;
    const float4 v = *(const float4*)(X + i);
    us4 o = { f2bf(v.x), f2bf(v.y), f2bf(v.z), f2bf(v.w) };
    *(us4*)(Xb + i) = o;
}

// causal softmax, single-pass (register-cached), in-place bf16.
// Zeroes only cols [n, diag-block edge) — all PV ever reads.
__global__ __launch_bounds__(256) void softmax_causal_bf16(u16* __restrict__ S) {
    __shared__ float red[4];
    __shared__ float bc;
    const int i = blockIdx.x;
    u16* row = S + (size_t)i * SEQ;
    const int n = i + 1;
    const int tid = threadIdx.x;
    const int zend = (i & ~127) + 128;

    float v[16];
    float m = -3.4e38f;
#pragma unroll
    for (int t = 0; t < 16; ++t) {
        const int j = tid + (t << 8);
        if (j < n) { v[t] = bf2f(row[j]); m = fmaxf(m, v[t]); }
    }
#pragma unroll
    for (int o = 32; o > 0; o >>= 1) m = fmaxf(m, __shfl_down(m, o));
    if ((tid & 63) == 0) red[tid >> 6] = m;
    __syncthreads();
    if (tid == 0) bc = fmaxf(fmaxf(red[0], red[1]), fmaxf(red[2], red[3]));
    __syncthreads();
    m = bc;

    float s = 0.f;
#pragma unroll
    for (int t = 0; t < 16; ++t) {
        const int j = tid + (t << 8);
        if (j < n) { v[t] = __expf(v[t] - m); s += v[t]; }
    }
#pragma unroll
    for (int o = 32; o > 0; o >>= 1) s += __shfl_down(s, o);
    if ((tid & 63) == 0) red[tid >> 6] = s;
    __syncthreads();
    if (tid == 0) bc = 1.0f / (red[0] + red[1] + red[2] + red[3]);
    __syncthreads();
    const float inv = bc;

#pragma unroll
    for (int t = 0; t < 16; ++t) {
        const int j = tid + (t << 8);
        if (j < n) row[j] = f2bf(v[t] * inv);
        else if (j < zend) row[j] = 0;
    }
}

// O[row] += partials, rows 1024..4095; one block per row, float4 lanes
__global__ __launch_bounds__(256) void reduce_pv(float* __restrict__ O,
                                                 const float* __restrict__ P) {
    const int r = blockIdx.x;  // 0..3071
    const int row = 1024 + r;
    const int col = threadIdx.x * 4;
    float4 a = *(const float4*)(O + (size_t)row * 1024 + col);
    const float4 b1 = *(const float4*)(P + (size_t)r * 1024 + col);
    a.x += b1.x; a.y += b1.y; a.z += b1.z; a.w += b1.w;
    if (row >= 2048) {
        const float4 b2 = *(const float4*)(P + (size_t)3072 * 1024 +
                                           (size_t)(row - 2048) * 1024 + col);
        a.x += b2.x; a.y += b2.y; a.z += b2.z; a.w += b2.w;
    }
    if (row >= 3072) {
        const float4 b3 = *(const float4*)(P + (size_t)5120 * 1024 +
                                           (size_t)(row - 3072) * 1024 + col);
        a.x += b3.x; a.y += b3.y; a.z += b3.z; a.w += b3.w;
    }
    *(float4*)(O + (size_t)row * 1024 + col) = a;
}

extern "C" void kernel_launch(void* const* d_in, const int* in_sizes, int n_in,
                              void* d_out, int out_size, void* d_ws, size_t ws_size,
                              hipStream_t stream) {
    const float* x  = (const float*)d_in[0];
    const float* Wq = (const float*)d_in[1];
    const float* Wk = (const float*)d_in[2];
    const float* Wv = (const float*)d_in[3];

    // ws: xb 8MB | Wt 6MB | QK [4096][2048] 16MB | Vt 8MB | S 32MB | Ppart 24MB = 94 MB
    u16* xb    = (u16*)d_ws;
    u16* Wt    = xb  + (size_t)SEQ * DIM;
    u16* QK    = Wt  + (size_t)3072 * DIM;
    u16* Vt    = QK  + (size_t)SEQ * 2048;
    u16* S     = Vt  + (size_t)DIM * SEQ;
    float* Ppart = (float*)(S + (size_t)SEQ * SEQ);

    cast_bf16<<<SEQ * DIM / 1024, 256, 0, stream>>>(x, xb);
    transpose_cast<<<dim3(32, 32, 3), 256, 0, stream>>>(Wq, Wk, Wv, Wt);

    // [Q|K] = x @ [Wq|Wk] (Q scaled 1/32); V columns stream out as V^T. 768 blocks.
    gemm_nt<0><<<dim3(24, 32), 256, 0, stream>>>(
        xb, Wt, QK, nullptr, Vt, DIM, DIM, 2048, DIM, 0.03125f);

    // S = Q @ K^T, lower-triangle blocks. 528 active blocks.
    gemm_nt<1><<<dim3(32, 32), 256, 0, stream>>>(
        QK, QK + 1024, S, nullptr, nullptr, 2048, 2048, SEQ, DIM, 1.0f);

    softmax_causal_bf16<<<SEQ, 256, 0, stream>>>(S);

    // O = P @ Vt^T, split-K (1024-chunks, causal-bounded). 640 active blocks.
    gemm_nt<2><<<dim3(8, 32, 4), 256, 0, stream>>>(
        S, Vt, d_out, Ppart, nullptr, SEQ, SEQ, DIM, SEQ, 1.0f);

    reduce_pv<<<3072, 256, 0, stream>>>((float*)d_out, Ppart);
}